// Round 2
// baseline (264.692 us; speedup 1.0000x reference)
//
#include <hip/hip_runtime.h>

#define NPIX 16384

typedef _Float16 f16;
typedef __attribute__((ext_vector_type(8))) _Float16 half8;
typedef __attribute__((ext_vector_type(4))) _Float16 half4;
typedef __attribute__((ext_vector_type(4))) float f32x4;

// Load 8 consecutive floats, convert to half8 fragment.
__device__ inline half8 cvt8(const float* __restrict__ p) {
  float4 a = *(const float4*)p;
  float4 b = *(const float4*)(p + 4);
  half8 r;
  r[0] = (f16)a.x; r[1] = (f16)a.y; r[2] = (f16)a.z; r[3] = (f16)a.w;
  r[4] = (f16)b.x; r[5] = (f16)b.y; r[6] = (f16)b.z; r[7] = (f16)b.w;
  return r;
}

// Transpose+convert: y [16][8][NPIX] f32 + noise [16][8][NPIX] f32
//   -> feats[p][b][n] f16  ([NPIX][16][16], 8 MB in d_ws)
// Grid: (NPIX/64)*16 blocks of 256. Block = 64 pixels x one batch b (all 16 n).
__global__ __launch_bounds__(256) void pack_feats(
    const float* __restrict__ y,
    const float* __restrict__ nz,
    f16* __restrict__ out)
{
  __shared__ f16 tile[16][68];  // [n][p], padded stride
  const int bb = blockIdx.x & 15;
  const int p0 = (blockIdx.x >> 4) << 6;
  const int t = threadIdx.x;
  {
    const int n = t >> 4, pg = t & 15;
    const float* src = (n < 8) ? (y + (bb * 8 + n) * NPIX)
                               : (nz + (bb * 8 + (n - 8)) * NPIX);
    float4 v = *(const float4*)(src + p0 + pg * 4);  // coalesced
    tile[n][pg * 4 + 0] = (f16)v.x;
    tile[n][pg * 4 + 1] = (f16)v.y;
    tile[n][pg * 4 + 2] = (f16)v.z;
    tile[n][pg * 4 + 3] = (f16)v.w;
  }
  __syncthreads();
  {
    const int pp = t >> 2, q = t & 3;
    half4 w;
    w[0] = tile[q * 4 + 0][pp];
    w[1] = tile[q * 4 + 1][pp];
    w[2] = tile[q * 4 + 2][pp];
    w[3] = tile[q * 4 + 3][pp];
    *(half4*)(out + (p0 + pp) * 256 + bb * 16 + q * 4) = w;  // 8B store
  }
}

// One wave per pixel, 4 waves/block.
// einsum: D[b][m] = sum_{k,n} feats[b][nb(p,k)][n] * wmap[p][k][m][n]  (K=144 pad 160)
// MFMA f32_16x16x32_f16: A[i=lane&15][k=q*8+j], B[j=lane&15][k], D: col=lane&15, row=q*4+r.
__global__ __launch_bounds__(256) void lr_main(
    const f16*  __restrict__ feats,   // [NPIX][16][16] f16 (ws)
    const float* __restrict__ wmap,   // [NPIX][9][16][16] f32
    const float* __restrict__ noise2, // [16][NPIX][8] f32
    const float* __restrict__ w1,     // [64][24] f32
    const float* __restrict__ b1,     // [64] f32
    const float* __restrict__ w2,     // [8][64] f32
    const float* __restrict__ b2,     // [8] f32
    const int*  __restrict__ nidx,    // [NPIX][9] i32
    float* __restrict__ outp)         // [16][8][NPIX] f32
{
  __shared__ f16 lds_i[4][16 * 24];  // per-wave intermediate [b][m], stride 24 (48B)
  __shared__ f16 lds_h[4][16 * 72];  // per-wave h [b][j], stride 72 (144B)

  const int t = threadIdx.x;
  const int wv = t >> 6;
  const int l = t & 63;
  const int col = l & 15;
  const int q = l >> 4;
  const int p = (blockIdx.x << 2) + wv;

  f16* li = lds_i[wv];
  f16* lh = lds_h[wv];

  const int n0 = (q & 1) * 8;   // n-half within the 32-wide k-chunk
  const int kh = q >> 1;        // which of the chunk's two k's

  // ---- einsum: 5 MFMAs over kk = (k,n), kk padded 144 -> 160 ----
  f32x4 acc = {0.f, 0.f, 0.f, 0.f};
  const int* nrow = nidx + p * 9;
  #pragma unroll
  for (int c = 0; c < 4; ++c) {
    const int k = 2 * c + kh;
    const int nb = nrow[k];
    half8 a = *(const half8*)(feats + nb * 256 + col * 16 + n0);   // 512B/neighbor per wave
    half8 bf = cvt8(wmap + ((p * 9 + k) * 16 + col) * 16 + n0);    // 1KB contiguous per k
    acc = __builtin_amdgcn_mfma_f32_16x16x32_f16(a, bf, acc, 0, 0, 0);
  }
  {
    half8 a = {0, 0, 0, 0, 0, 0, 0, 0};
    half8 bf = {0, 0, 0, 0, 0, 0, 0, 0};
    if (q < 2) {  // kk 128..143 (k=8); 144..159 zero pad
      const int nb = nrow[8];
      a = *(const half8*)(feats + nb * 256 + col * 16 + n0);
      bf = cvt8(wmap + ((p * 9 + 8) * 16 + col) * 16 + n0);
    }
    acc = __builtin_amdgcn_mfma_f32_16x16x32_f16(a, bf, acc, 0, 0, 0);
  }

  // intermediate D[b=q*4+r][m=col] -> LDS (f16) for A-layout re-read
  #pragma unroll
  for (int r = 0; r < 4; ++r) {
    li[(q * 4 + r) * 24 + col] = (f16)acc[r];
  }
  __syncthreads();

  // ---- MLP1: h[b][j] = relu(mlp_in[b][0..23] . w1[j][:] + b1[j]); K=24 pad 32, N=64 ----
  half8 amlp = {0, 0, 0, 0, 0, 0, 0, 0};
  if (q < 2)       amlp = *(const half8*)(li + col * 24 + q * 8);   // d 0..15: intermediate
  else if (q == 2) amlp = cvt8(noise2 + (col * NPIX + p) * 8);      // d 16..23: noise2
  // q==3: d 24..31 zero pad

  const f32x4 zero4 = {0.f, 0.f, 0.f, 0.f};
  #pragma unroll
  for (int jc = 0; jc < 4; ++jc) {
    half8 wf = {0, 0, 0, 0, 0, 0, 0, 0};
    if (q < 3) wf = cvt8(w1 + (jc * 16 + col) * 24 + q * 8);
    f32x4 h4 = __builtin_amdgcn_mfma_f32_16x16x32_f16(amlp, wf, zero4, 0, 0, 0);
    const float b1f = b1[jc * 16 + col];
    #pragma unroll
    for (int r = 0; r < 4; ++r) {
      float hv = fmaxf(h4[r] + b1f, 0.f);
      lh[(q * 4 + r) * 72 + jc * 16 + col] = (f16)hv;
    }
  }
  __syncthreads();

  // ---- MLP2: out[b][f] = h[b][:] . w2[f][:] + b2[f]; K=64, N=8 pad 16 ----
  f32x4 oacc = {0.f, 0.f, 0.f, 0.f};
  #pragma unroll
  for (int c2 = 0; c2 < 2; ++c2) {
    half8 a2 = *(const half8*)(lh + col * 72 + c2 * 32 + q * 8);
    half8 wf = {0, 0, 0, 0, 0, 0, 0, 0};
    if (col < 8) wf = cvt8(w2 + col * 64 + c2 * 32 + q * 8);
    oacc = __builtin_amdgcn_mfma_f32_16x16x32_f16(a2, wf, oacc, 0, 0, 0);
  }
  if (col < 8) {
    const float b2f = b2[col];
    #pragma unroll
    for (int r = 0; r < 4; ++r) {
      const int b = q * 4 + r;
      outp[(b * 8 + col) * NPIX + p] = oacc[r] + b2f;
    }
  }
}

extern "C" void kernel_launch(void* const* d_in, const int* in_sizes, int n_in,
                              void* d_out, int out_size, void* d_ws, size_t ws_size,
                              hipStream_t stream) {
  const float* y    = (const float*)d_in[0];
  const float* nz   = (const float*)d_in[1];
  const float* nz2  = (const float*)d_in[2];
  const float* wmap = (const float*)d_in[3];
  const float* w1   = (const float*)d_in[4];
  const float* b1   = (const float*)d_in[5];
  const float* w2   = (const float*)d_in[6];
  const float* b2   = (const float*)d_in[7];
  const int* nidx   = (const int*)d_in[8];
  float* outp = (float*)d_out;
  f16* feats  = (f16*)d_ws;   // 8 MB scratch: feats[NPIX][16][16] f16

  hipLaunchKernelGGL(pack_feats, dim3((NPIX / 64) * 16), dim3(256), 0, stream,
                     y, nz, feats);
  hipLaunchKernelGGL(lr_main, dim3(NPIX / 4), dim3(256), 0, stream,
                     feats, wmap, nz2, w1, b1, w2, b2, nidx, outp);
}